// Round 1
// 252.841 us; speedup vs baseline: 1.1097x; 1.1097x over previous
//
#include <hip/hip_runtime.h>

// SNN forward, round 5.
// convW: hi/lo precision split across wave pairs. 512 thr = 8 waves; wave pair
// wp owns 2 jj-rows x 3 m-tiles, hl=wv&1 picks hi or lo weight stream.
// acc drops 192->96 regs/wave -> compiler can prefetch A/B loads; 2 waves/SIMD
// forced via __launch_bounds__(512,2). hi+lo recombined through LDS with the
// identical expression u = hi + lo/2048 (bit-exact vs round 4).
// LIF kernels: unroll-16 batched loads.

typedef __attribute__((ext_vector_type(8))) _Float16 v8h;
typedef __attribute__((ext_vector_type(16))) float v16f;
typedef _Float16 half_t;

#define NB 32
#define NC 64
#define NT 129
#define TIN 128
#define NM 40
#define MSTR 144          // LDS per-slot stride: 16B-aligned, conflict-free
#define SROWB 5120        // global spike row bytes = 40*64*2

// ---- weights -> MFMA A-fragments, order [tap12][cq4][ct2][hl2][lane64]x16B ----
// A-frag (32x32x16 f16): lane holds A[co=ct*32+(lane&31)][ci=cq*16+(lane>>5)*8+jj]
__global__ void prep_wfrag(const float* __restrict__ w, uint4* __restrict__ wf) {
    int tid = blockIdx.x * 256 + threadIdx.x;   // 12288
    if (tid >= 12288) return;
    int lane = tid & 63;
    int rest = tid >> 6;
    int hl = rest & 1;
    int ct = (rest >> 1) & 1;
    int cq = (rest >> 2) & 3;
    int tap = rest >> 4;
    int kh = tap / 3, kw = tap % 3;
    int co = ct * 32 + (lane & 31);
    unsigned short o[8];
#pragma unroll
    for (int jj = 0; jj < 8; jj++) {
        int ci = cq * 16 + (lane >> 5) * 8 + jj;
        float wv = w[((co * 64 + ci) * 4 + kh) * 3 + kw];
        _Float16 hi = (_Float16)wv;
        _Float16 val = hl ? (_Float16)((wv - (float)hi) * 2048.0f) : hi;
        unsigned short us;
        __builtin_memcpy(&us, &val, 2);
        o[jj] = us;
    }
    uint4 r;
    __builtin_memcpy(&r, o, 16);
    wf[tid] = r;
}

// ---- conv1 (1->64ch, 4x3, pad(2,1)) + LIF1, unroll-8 row prefetch ----
__global__ void conv1_lif1(const float* __restrict__ x, const float* __restrict__ w1,
                           half_t* __restrict__ s1) {
    const int mg = blockIdx.x;        // 0..9
    const int b = blockIdx.y;
    const int c = threadIdx.x & 63;
    const int ml = threadIdx.x >> 6;  // 0..3
    const int m = mg * 4 + ml;
    float w[4][3];
#pragma unroll
    for (int kh = 0; kh < 4; kh++)
#pragma unroll
        for (int kw = 0; kw < 3; kw++) w[kh][kw] = w1[(c * 4 + kh) * 3 + kw];
    const float* xb = x + (size_t)b * TIN * NM;

    float xw[12][3];                  // rows tb-2 .. tb+9
#pragma unroll
    for (int rr = 0; rr < 12; rr++)
#pragma unroll
        for (int kw = 0; kw < 3; kw++) xw[rr][kw] = 0.f;
#pragma unroll
    for (int rr = 2; rr < 4; rr++)
#pragma unroll
        for (int kw = 0; kw < 3; kw++) {
            int mc = m - 1 + kw;
            xw[rr][kw] = ((unsigned)mc < (unsigned)NM) ? xb[(rr - 2) * NM + mc] : 0.f;
        }

    half_t* orow = s1 + ((size_t)b * NT * NM + m) * 64 + c;
    float v = 0.f;
    const float TAUc = 10.0f / 7.0f;

    for (int tb = 0; tb < NT; tb += 8) {
        // batch-load rows tb+2 .. tb+9 (independent of the recurrence)
#pragma unroll
        for (int q = 0; q < 8; q++) {
            int row = tb + 2 + q;
#pragma unroll
            for (int kw = 0; kw < 3; kw++) {
                int mc = m - 1 + kw;
                xw[4 + q][kw] = (row < TIN && (unsigned)mc < (unsigned)NM)
                                    ? xb[row * NM + mc] : 0.f;
            }
        }
        int kmax = (NT - tb) < 8 ? (NT - tb) : 8;
#pragma unroll
        for (int k = 0; k < 8; k++) {
            if (k < kmax) {
                float uacc = 0.f;
#pragma unroll
                for (int kh = 0; kh < 4; kh++)
#pragma unroll
                    for (int kw = 0; kw < 3; kw++) uacc += xw[k + kh][kw] * w[kh][kw];
                v = v + (uacc - v) / TAUc;
                float s = (v >= 1.0f) ? 1.0f : 0.0f;
                orow[(size_t)(tb + k) * NM * 64] = (half_t)s;
                if (v >= 1.0f) v = 0.0f;
            }
        }
#pragma unroll
        for (int rr = 0; rr < 4; rr++)
#pragma unroll
            for (int kw = 0; kw < 3; kw++) xw[rr][kw] = xw[8 + rr][kw];
    }
}

// ---- MFMA conv 64->64, 4x3 dilated, weight-streaming, hi/lo wave split.
// grid (17, B) x 512 thr. bx<16: r = bx%RMOD, jj0 = (bx/RMOD)*8; bx==16: r=0,
// jj0=(16/RMOD)*8. Wave wv: wp=wv>>1 owns jj-pair (jj0+2wp, jj0+2wp+1) x 3
// m-tiles {0,16,24}; hl=wv&1 selects hi or lo A-frag stream (6 accs = 96 regs).
template <int DH, int PH, int DW, int PW, int EXT, int RMOD>
__global__ __launch_bounds__(512, 2) void convW(const half_t* __restrict__ spk,
                                                const uint4* __restrict__ wfrag,
                                                float* __restrict__ u) {
    extern __shared__ char lds[];
    constexpr int LROWB = EXT * MSTR;
    constexpr int NCH = 11 * EXT * 8;           // 16B staging chunks
    const int tid = threadIdx.x;
    const int lane = tid & 63;
    const int wv = tid >> 6;                    // 0..7
    const int wp = wv >> 1;                     // 0..3 jj-pair
    const int hl = wv & 1;                      // 0=hi, 1=lo
    const int bx = blockIdx.x;
    const int b = blockIdx.y;
    int r, jj0;
    if (bx < 16) { r = bx % RMOD; jj0 = (bx / RMOD) * 8; }
    else         { r = 0;         jj0 = (16 / RMOD) * 8; }

    // ---- stage 11 lattice rows (zero-fill OOB), one barrier ----
    const char* spb = (const char*)spk + (size_t)b * NT * SROWB;
#pragma unroll
    for (int k = 0; k < (NCH + 511) / 512; k++) {
        int c = tid + k * 512;
        if (c < NCH) {
            int i = c / (EXT * 8);
            int rem = c - i * (EXT * 8);
            int s = rem >> 3;
            int ci8 = rem & 7;
            int tg = r - PH + DH * (jj0 + i);
            int md = s - PW;
            uint4 val = make_uint4(0u, 0u, 0u, 0u);
            if ((unsigned)tg < (unsigned)NT && (unsigned)md < (unsigned)NM)
                val = *(const uint4*)(spb + ((size_t)tg * NM + md) * 128 + ci8 * 16);
            *(uint4*)(lds + i * LROWB + s * MSTR + ci8 * 16) = val;
        }
    }
    __syncthreads();

    // ---- lane decode: pos-tile = 2jj x 16m ----
    const int pos = lane & 31;
    const int jl = pos >> 4;
    const int ml = pos & 15;
    const int hseg = lane >> 5;
    const int jj = jj0 + 2 * wp + jl;
    const int ldsrow = 2 * wp + jl;             // 0..7
    const int t = r + DH * jj;
    const int mtb[3] = {0, 16, 24};

    int baseB[3];
#pragma unroll
    for (int mt = 0; mt < 3; mt++)
        baseB[mt] = ldsrow * LROWB + (mtb[mt] + ml) * MSTR + hseg * 16;

    v16f acc[3][2];                             // [m-tile][co-tile], one hl stream
#pragma unroll
    for (int a = 0; a < 3; a++)
#pragma unroll
        for (int c2 = 0; c2 < 2; c2++) acc[a][c2] = (v16f)(0.0f);

    const uint4* wpt = wfrag + lane + hl * 64;  // hl selects hi/lo stream
#pragma unroll
    for (int tap = 0; tap < 12; tap++) {
        const int kh = tap / 3, kw = tap % 3;
        const int bo = kh * LROWB + kw * (DW * MSTR);
#pragma unroll
        for (int cq = 0; cq < 4; cq++) {
            v8h B0 = *(const v8h*)(lds + baseB[0] + bo + cq * 32);
            v8h B1 = *(const v8h*)(lds + baseB[1] + bo + cq * 32);
            v8h B2 = *(const v8h*)(lds + baseB[2] + bo + cq * 32);
            const uint4* wq = wpt + (tap * 4 + cq) * 256;
            v8h A0 = *(const v8h*)(wq);         // ct0, this hl
            v8h A1 = *(const v8h*)(wq + 128);   // ct1, this hl
            acc[0][0] = __builtin_amdgcn_mfma_f32_32x32x16_f16(A0, B0, acc[0][0], 0, 0, 0);
            acc[0][1] = __builtin_amdgcn_mfma_f32_32x32x16_f16(A1, B0, acc[0][1], 0, 0, 0);
            acc[1][0] = __builtin_amdgcn_mfma_f32_32x32x16_f16(A0, B1, acc[1][0], 0, 0, 0);
            acc[1][1] = __builtin_amdgcn_mfma_f32_32x32x16_f16(A1, B1, acc[1][1], 0, 0, 0);
            acc[2][0] = __builtin_amdgcn_mfma_f32_32x32x16_f16(A0, B2, acc[2][0], 0, 0, 0);
            acc[2][1] = __builtin_amdgcn_mfma_f32_32x32x16_f16(A1, B2, acc[2][1], 0, 0, 0);
        }
    }

    // ---- combine: lo wave -> LDS (reuse staging buffer), hi wave adds+writes.
    // u = hi + lo/2048, identical arithmetic/order to round 4 (bit-exact).
    const float invs = 1.0f / 2048.0f;
    float4* lred = (float4*)lds;                // 4 wp x 8 chunks x 64 lanes x 16B = 32KB
    __syncthreads();                            // all B-frag LDS reads done
#pragma unroll
    for (int mt = 0; mt < 3; mt++) {
        if (hl) {
#pragma unroll
            for (int ct = 0; ct < 2; ct++)
#pragma unroll
                for (int g = 0; g < 4; g++) {
                    float4 vv;
                    vv.x = acc[mt][ct][4 * g + 0];
                    vv.y = acc[mt][ct][4 * g + 1];
                    vv.z = acc[mt][ct][4 * g + 2];
                    vv.w = acc[mt][ct][4 * g + 3];
                    lred[(wp * 8 + ct * 4 + g) * 64 + lane] = vv;
                }
        }
        __syncthreads();
        if (!hl && t < NT) {
            int m = mtb[mt] + ml;
            float* base = u + ((size_t)(b * NT + t) * NM + m) * 64;
#pragma unroll
            for (int ct = 0; ct < 2; ct++)
#pragma unroll
                for (int g = 0; g < 4; g++) {
                    float4 lo = lred[(wp * 8 + ct * 4 + g) * 64 + lane];
                    int co = ct * 32 + 8 * g + 4 * hseg;
                    float4 val;
                    val.x = acc[mt][ct][4 * g + 0] + lo.x * invs;
                    val.y = acc[mt][ct][4 * g + 1] + lo.y * invs;
                    val.z = acc[mt][ct][4 * g + 2] + lo.z * invs;
                    val.w = acc[mt][ct][4 * g + 3] + lo.w * invs;
                    *(float4*)(base + co) = val;
                }
        }
        __syncthreads();
    }
}

// ---- LIF over T: u fp32 -> compact f16 spikes, unroll-16 ----
__global__ void lif_spikes(const float* __restrict__ u, half_t* __restrict__ s2) {
    int tid = blockIdx.x * 256 + threadIdx.x;   // 81920
    int b = tid / 2560;
    int cm = tid % 2560;
    const float* up = u + (size_t)b * NT * 2560 + cm;
    half_t* sp = s2 + (size_t)b * NT * 2560 + cm;
    float v = 0.f;
    const float TAUc = 10.0f / 7.0f;
    for (int tb = 0; tb < 128; tb += 16) {
        float uu[16];
#pragma unroll
        for (int k = 0; k < 16; k++) uu[k] = up[(size_t)(tb + k) * 2560];
#pragma unroll
        for (int k = 0; k < 16; k++) {
            v = v + (uu[k] - v) / TAUc;
            float s = (v >= 1.0f) ? 1.0f : 0.0f;
            sp[(size_t)(tb + k) * 2560] = (half_t)s;
            if (v >= 1.0f) v = 0.f;
        }
    }
    float uu = up[(size_t)128 * 2560];
    v = v + (uu - v) / TAUc;
    sp[(size_t)128 * 2560] = (half_t)((v >= 1.0f) ? 1.0f : 0.0f);
}

// ---- LIF3: spike counts only (mean commutes with FC), unroll-16 ----
__global__ void lif_sum(const float* __restrict__ u, float* __restrict__ hsum) {
    int tid = blockIdx.x * 256 + threadIdx.x;   // 81920
    int b = tid / 2560;
    int cm = tid % 2560;                         // = m*64 + co
    int m = cm >> 6;
    int co = cm & 63;
    const float* up = u + (size_t)b * NT * 2560 + cm;
    float v = 0.f, cnt = 0.f;
    const float TAUc = 10.0f / 7.0f;
    for (int tb = 0; tb < 128; tb += 16) {
        float uu[16];
#pragma unroll
        for (int k = 0; k < 16; k++) uu[k] = up[(size_t)(tb + k) * 2560];
#pragma unroll
        for (int k = 0; k < 16; k++) {
            v = v + (uu[k] - v) / TAUc;
            if (v >= 1.0f) { cnt += 1.0f; v = 0.f; }
        }
    }
    float uu = up[(size_t)128 * 2560];
    v = v + (uu - v) / TAUc;
    if (v >= 1.0f) cnt += 1.0f;
    hsum[b * 2560 + co * NM + m] = cnt;          // feature index = c*40 + m
}

// ---- FC on counts: y[b,k] = bf[k] + (sum_cm cnt*wf[k,cm]) / 129 ----
__global__ void fc_out(const float* __restrict__ hsum, const float* __restrict__ wf,
                       const float* __restrict__ bfv, float* __restrict__ out) {
    int b = blockIdx.x;
    int tid = threadIdx.x;
    float p[12];
#pragma unroll
    for (int k = 0; k < 12; k++) p[k] = 0.0f;
    for (int cm = tid; cm < NC * NM; cm += 256) {
        float h = hsum[b * NC * NM + cm];
#pragma unroll
        for (int k = 0; k < 12; k++) p[k] += h * wf[k * (NC * NM) + cm];
    }
    __shared__ float red[12][4];
    int lane = tid & 63, w = tid >> 6;
#pragma unroll
    for (int k = 0; k < 12; k++) {
        float s = p[k];
#pragma unroll
        for (int off = 32; off > 0; off >>= 1) s += __shfl_down(s, off, 64);
        if (lane == 0) red[k][w] = s;
    }
    __syncthreads();
    if (tid < 12) {
        float s = red[tid][0] + red[tid][1] + red[tid][2] + red[tid][3];
        out[b * 12 + tid] = bfv[tid] + s / 129.0f;
    }
}

extern "C" void kernel_launch(void* const* d_in, const int* in_sizes, int n_in,
                              void* d_out, int out_size, void* d_ws, size_t ws_size,
                              hipStream_t stream) {
    const float* x  = (const float*)d_in[0];
    const float* w1 = (const float*)d_in[1];
    const float* w2 = (const float*)d_in[2];
    const float* w3 = (const float*)d_in[3];
    const float* wf = (const float*)d_in[4];
    const float* bf = (const float*)d_in[5];
    float* out = (float*)d_out;

    char* ws = (char*)d_ws;
    half_t* s1  = (half_t*)ws;                      // 21,135,360 B
    half_t* s2  = (half_t*)(ws + 21135360);         // 21,135,360 B
    float*  u   = (float*)(ws + 42270720);          // 42,270,720 B
    uint4*  wf2 = (uint4*)(ws + 84541440);          // 196,608 B
    uint4*  wf3 = (uint4*)(ws + 84738048);          // 196,608 B
    float* hsum = (float*)(ws + 84934656);          // 327,680 B (end ~85.3 MB)

    constexpr int LDS2 = 11 * 46 * MSTR;            // 72,864 B
    constexpr int LDS3 = 11 * 58 * MSTR;            // 91,872 B
    static bool attr_set = false;
    if (!attr_set) {
        hipFuncSetAttribute((const void*)&convW<4, 6, 3, 3, 46, 4>,
                            hipFuncAttributeMaxDynamicSharedMemorySize, LDS2);
        hipFuncSetAttribute((const void*)&convW<16, 24, 9, 9, 58, 16>,
                            hipFuncAttributeMaxDynamicSharedMemorySize, LDS3);
        attr_set = true;
    }

    prep_wfrag<<<48, 256, 0, stream>>>(w2, wf2);
    prep_wfrag<<<48, 256, 0, stream>>>(w3, wf3);

    conv1_lif1<<<dim3(10, 32), 256, 0, stream>>>(x, w1, s1);

    convW<4, 6, 3, 3, 46, 4><<<dim3(17, 32), 512, LDS2, stream>>>(s1, wf2, u);
    lif_spikes<<<320, 256, 0, stream>>>(u, s2);

    convW<16, 24, 9, 9, 58, 16><<<dim3(17, 32), 512, LDS3, stream>>>(s2, wf3, u);
    lif_sum<<<320, 256, 0, stream>>>(u, hsum);

    fc_out<<<32, 256, 0, stream>>>(hsum, wf, bf, out);
}

// Round 2
// 248.305 us; speedup vs baseline: 1.1300x; 1.0183x over previous
//
#include <hip/hip_runtime.h>

// SNN forward, round 6.
// convW: A-frags staged per-tap into a double-buffered LDS region (2x16KB),
// prefetched one tap ahead (2 dwordx4 per thread, issued before the tap's
// MFMAs, written after, 1 barrier/tap). K-loop has ZERO global loads: only
// ds_read (2 A + 3 B per (tap,cq)) which hipcc pipelines with fine lgkmcnt.
// Spike tile shrunk 58->40 slots + shared zero-slot (clamped read bases) to
// fit the A-buffer: LDS = 96,320 B. u accumulation order bit-exact vs r5.

typedef __attribute__((ext_vector_type(8))) _Float16 v8h;
typedef __attribute__((ext_vector_type(16))) float v16f;
typedef _Float16 half_t;

#define NB 32
#define NC 64
#define NT 129
#define TIN 128
#define NM 40
#define MSTR 144          // LDS per-slot stride: 16B-aligned
#define SROWB 5120        // global spike row bytes = 40*64*2

// ---- weights -> MFMA A-fragments, order [tap12][cq4][ct2][hl2][lane64]x16B ----
// A-frag (32x32x16 f16): lane holds A[co=ct*32+(lane&31)][ci=cq*16+(lane>>5)*8+jj]
__global__ void prep_wfrag(const float* __restrict__ w, uint4* __restrict__ wf) {
    int tid = blockIdx.x * 256 + threadIdx.x;   // 12288
    if (tid >= 12288) return;
    int lane = tid & 63;
    int rest = tid >> 6;
    int hl = rest & 1;
    int ct = (rest >> 1) & 1;
    int cq = (rest >> 2) & 3;
    int tap = rest >> 4;
    int kh = tap / 3, kw = tap % 3;
    int co = ct * 32 + (lane & 31);
    unsigned short o[8];
#pragma unroll
    for (int jj = 0; jj < 8; jj++) {
        int ci = cq * 16 + (lane >> 5) * 8 + jj;
        float wv = w[((co * 64 + ci) * 4 + kh) * 3 + kw];
        _Float16 hi = (_Float16)wv;
        _Float16 val = hl ? (_Float16)((wv - (float)hi) * 2048.0f) : hi;
        unsigned short us;
        __builtin_memcpy(&us, &val, 2);
        o[jj] = us;
    }
    uint4 r;
    __builtin_memcpy(&r, o, 16);
    wf[tid] = r;
}

// ---- conv1 (1->64ch, 4x3, pad(2,1)) + LIF1, unroll-8 row prefetch ----
__global__ void conv1_lif1(const float* __restrict__ x, const float* __restrict__ w1,
                           half_t* __restrict__ s1) {
    const int mg = blockIdx.x;        // 0..9
    const int b = blockIdx.y;
    const int c = threadIdx.x & 63;
    const int ml = threadIdx.x >> 6;  // 0..3
    const int m = mg * 4 + ml;
    float w[4][3];
#pragma unroll
    for (int kh = 0; kh < 4; kh++)
#pragma unroll
        for (int kw = 0; kw < 3; kw++) w[kh][kw] = w1[(c * 4 + kh) * 3 + kw];
    const float* xb = x + (size_t)b * TIN * NM;

    float xw[12][3];                  // rows tb-2 .. tb+9
#pragma unroll
    for (int rr = 0; rr < 12; rr++)
#pragma unroll
        for (int kw = 0; kw < 3; kw++) xw[rr][kw] = 0.f;
#pragma unroll
    for (int rr = 2; rr < 4; rr++)
#pragma unroll
        for (int kw = 0; kw < 3; kw++) {
            int mc = m - 1 + kw;
            xw[rr][kw] = ((unsigned)mc < (unsigned)NM) ? xb[(rr - 2) * NM + mc] : 0.f;
        }

    half_t* orow = s1 + ((size_t)b * NT * NM + m) * 64 + c;
    float v = 0.f;
    const float TAUc = 10.0f / 7.0f;

    for (int tb = 0; tb < NT; tb += 8) {
#pragma unroll
        for (int q = 0; q < 8; q++) {
            int row = tb + 2 + q;
#pragma unroll
            for (int kw = 0; kw < 3; kw++) {
                int mc = m - 1 + kw;
                xw[4 + q][kw] = (row < TIN && (unsigned)mc < (unsigned)NM)
                                    ? xb[row * NM + mc] : 0.f;
            }
        }
        int kmax = (NT - tb) < 8 ? (NT - tb) : 8;
#pragma unroll
        for (int k = 0; k < 8; k++) {
            if (k < kmax) {
                float uacc = 0.f;
#pragma unroll
                for (int kh = 0; kh < 4; kh++)
#pragma unroll
                    for (int kw = 0; kw < 3; kw++) uacc += xw[k + kh][kw] * w[kh][kw];
                v = v + (uacc - v) / TAUc;
                float s = (v >= 1.0f) ? 1.0f : 0.0f;
                orow[(size_t)(tb + k) * NM * 64] = (half_t)s;
                if (v >= 1.0f) v = 0.0f;
            }
        }
#pragma unroll
        for (int rr = 0; rr < 4; rr++)
#pragma unroll
            for (int kw = 0; kw < 3; kw++) xw[rr][kw] = xw[8 + rr][kw];
    }
}

// ---- MFMA conv 64->64, 4x3 dilated. A-frags via LDS double-buffer.
// grid (17, B) x 512 thr. bx<16: r = bx%RMOD, jj0 = (bx/RMOD)*8; bx==16: r=0,
// jj0=(16/RMOD)*8. Wave wv: wp=wv>>1 owns jj-pair (jj0+2wp, jj0+2wp+1) x 3
// m-tiles {0,16,24}; hl=wv&1 selects hi or lo A-frag stream (6 accs).
template <int DH, int PH, int DW, int PW, int RMOD>
__global__ __launch_bounds__(512, 2) void convW(const half_t* __restrict__ spk,
                                                const uint4* __restrict__ wfrag,
                                                float* __restrict__ u) {
    extern __shared__ char lds[];
    constexpr int LROWB = 40 * MSTR;            // 5760 B per lattice row
    constexpr int ZOFF = 11 * LROWB;            // 63360: shared 144B zero slot
    constexpr int ABUF = 63552;                 // A double-buffer (2 x 16384)
    constexpr int NCH = 11 * 40 * 8;            // 3520 16B staging chunks
    const int tid = threadIdx.x;
    const int lane = tid & 63;
    const int wv = tid >> 6;                    // 0..7
    const int wp = wv >> 1;                     // 0..3 jj-pair
    const int hl = wv & 1;                      // 0=hi, 1=lo
    const int bx = blockIdx.x;
    const int b = blockIdx.y;
    int r, jj0;
    if (bx < 16) { r = bx % RMOD; jj0 = (bx / RMOD) * 8; }
    else         { r = 0;         jj0 = (16 / RMOD) * 8; }

    // ---- stage 11 lattice rows x 40 valid m-slots (zero-fill OOB t-rows) ----
    const char* spb = (const char*)spk + (size_t)b * NT * SROWB;
#pragma unroll
    for (int k = 0; k < 7; k++) {
        int c = tid + k * 512;
        if (c < NCH) {
            int i = c / 320;
            int rem = c - i * 320;
            int s = rem >> 3;                   // m-slot 0..39 == md
            int ci8 = rem & 7;
            int tg = r - PH + DH * (jj0 + i);
            uint4 val = make_uint4(0u, 0u, 0u, 0u);
            if ((unsigned)tg < (unsigned)NT)
                val = *(const uint4*)(spb + ((size_t)tg * NM + s) * 128 + ci8 * 16);
            *(uint4*)(lds + i * LROWB + s * MSTR + ci8 * 16) = val;
        }
    }
    // shared zero slot for OOB m reads
    if (tid < 9) *(uint4*)(lds + ZOFF + tid * 16) = make_uint4(0u, 0u, 0u, 0u);
    // stage A-frags for tap 0 into buffer 0
    {
        const uint4* g0 = wfrag + tid * 2;
        uint4 v0 = g0[0], v1 = g0[1];
        uint4* dst = (uint4*)(lds + ABUF + tid * 32);
        dst[0] = v0; dst[1] = v1;
    }
    __syncthreads();

    // ---- lane decode: pos-tile = 2jj x 16m ----
    const int pos = lane & 31;
    const int jl = pos >> 4;
    const int ml = pos & 15;
    const int hseg = lane >> 5;
    const int jj = jj0 + 2 * wp + jl;
    const int ldsrow = 2 * wp + jl;             // 0..7
    const int t = r + DH * jj;
    const int mtb[3] = {0, 16, 24};

    // clamped B-read bases: P = base if m in range, else zero slot; RS = row step
    int P[3][3], RS[3][3];
#pragma unroll
    for (int mt = 0; mt < 3; mt++)
#pragma unroll
        for (int kw = 0; kw < 3; kw++) {
            int md = mtb[mt] + ml + kw * DW - PW;
            bool ok = (unsigned)md < 40u;
            P[mt][kw] = ok ? (ldsrow * LROWB + md * MSTR + hseg * 16)
                           : (ZOFF + hseg * 16);
            RS[mt][kw] = ok ? LROWB : 0;
        }

    v16f acc[3][2];                             // [m-tile][co-tile], one hl stream
#pragma unroll
    for (int a = 0; a < 3; a++)
#pragma unroll
        for (int c2 = 0; c2 < 2; c2++) acc[a][c2] = (v16f)(0.0f);

    const int abase = ABUF + hl * 1024 + lane * 16;
#pragma unroll
    for (int tap = 0; tap < 12; tap++) {
        const int kh = tap / 3, kw = tap % 3;
        uint4 an0, an1;
        if (tap < 11) {                         // prefetch next tap's A-frags
            const uint4* g = wfrag + (tap + 1) * 1024 + tid * 2;
            an0 = g[0]; an1 = g[1];
        }
        const int a0 = P[0][kw] + kh * RS[0][kw];
        const int a1 = P[1][kw] + kh * RS[1][kw];
        const int a2 = P[2][kw] + kh * RS[2][kw];
        const int toff = (tap & 1) * 16384;
#pragma unroll
        for (int cq = 0; cq < 4; cq++) {
            v8h B0 = *(const v8h*)(lds + a0 + cq * 32);
            v8h B1 = *(const v8h*)(lds + a1 + cq * 32);
            v8h B2 = *(const v8h*)(lds + a2 + cq * 32);
            v8h A0 = *(const v8h*)(lds + abase + toff + cq * 4096);          // ct0
            v8h A1 = *(const v8h*)(lds + abase + toff + cq * 4096 + 2048);   // ct1
            acc[0][0] = __builtin_amdgcn_mfma_f32_32x32x16_f16(A0, B0, acc[0][0], 0, 0, 0);
            acc[0][1] = __builtin_amdgcn_mfma_f32_32x32x16_f16(A1, B0, acc[0][1], 0, 0, 0);
            acc[1][0] = __builtin_amdgcn_mfma_f32_32x32x16_f16(A0, B1, acc[1][0], 0, 0, 0);
            acc[1][1] = __builtin_amdgcn_mfma_f32_32x32x16_f16(A1, B1, acc[1][1], 0, 0, 0);
            acc[2][0] = __builtin_amdgcn_mfma_f32_32x32x16_f16(A0, B2, acc[2][0], 0, 0, 0);
            acc[2][1] = __builtin_amdgcn_mfma_f32_32x32x16_f16(A1, B2, acc[2][1], 0, 0, 0);
        }
        if (tap < 11) {                         // write next tap into other buffer
            uint4* dst = (uint4*)(lds + ABUF + ((tap + 1) & 1) * 16384 + tid * 32);
            dst[0] = an0; dst[1] = an1;
        }
        __syncthreads();
    }

    // ---- combine: lo wave -> LDS (low region, K-loop done), hi wave adds+writes.
    // u = hi + lo/2048, identical arithmetic/order (bit-exact).
    const float invs = 1.0f / 2048.0f;
    float4* lred = (float4*)lds;                // 4 wp x 8 chunks x 64 lanes x 16B = 32KB
#pragma unroll
    for (int mt = 0; mt < 3; mt++) {
        if (hl) {
#pragma unroll
            for (int ct = 0; ct < 2; ct++)
#pragma unroll
                for (int g = 0; g < 4; g++) {
                    float4 vv;
                    vv.x = acc[mt][ct][4 * g + 0];
                    vv.y = acc[mt][ct][4 * g + 1];
                    vv.z = acc[mt][ct][4 * g + 2];
                    vv.w = acc[mt][ct][4 * g + 3];
                    lred[(wp * 8 + ct * 4 + g) * 64 + lane] = vv;
                }
        }
        __syncthreads();
        if (!hl && t < NT) {
            int m = mtb[mt] + ml;
            float* base = u + ((size_t)(b * NT + t) * NM + m) * 64;
#pragma unroll
            for (int ct = 0; ct < 2; ct++)
#pragma unroll
                for (int g = 0; g < 4; g++) {
                    float4 lo = lred[(wp * 8 + ct * 4 + g) * 64 + lane];
                    int co = ct * 32 + 8 * g + 4 * hseg;
                    float4 val;
                    val.x = acc[mt][ct][4 * g + 0] + lo.x * invs;
                    val.y = acc[mt][ct][4 * g + 1] + lo.y * invs;
                    val.z = acc[mt][ct][4 * g + 2] + lo.z * invs;
                    val.w = acc[mt][ct][4 * g + 3] + lo.w * invs;
                    *(float4*)(base + co) = val;
                }
        }
        __syncthreads();
    }
}

// ---- LIF over T: u fp32 -> compact f16 spikes, unroll-16 ----
__global__ void lif_spikes(const float* __restrict__ u, half_t* __restrict__ s2) {
    int tid = blockIdx.x * 256 + threadIdx.x;   // 81920
    int b = tid / 2560;
    int cm = tid % 2560;
    const float* up = u + (size_t)b * NT * 2560 + cm;
    half_t* sp = s2 + (size_t)b * NT * 2560 + cm;
    float v = 0.f;
    const float TAUc = 10.0f / 7.0f;
    for (int tb = 0; tb < 128; tb += 16) {
        float uu[16];
#pragma unroll
        for (int k = 0; k < 16; k++) uu[k] = up[(size_t)(tb + k) * 2560];
#pragma unroll
        for (int k = 0; k < 16; k++) {
            v = v + (uu[k] - v) / TAUc;
            float s = (v >= 1.0f) ? 1.0f : 0.0f;
            sp[(size_t)(tb + k) * 2560] = (half_t)s;
            if (v >= 1.0f) v = 0.f;
        }
    }
    float uu = up[(size_t)128 * 2560];
    v = v + (uu - v) / TAUc;
    sp[(size_t)128 * 2560] = (half_t)((v >= 1.0f) ? 1.0f : 0.0f);
}

// ---- LIF3: spike counts only (mean commutes with FC), unroll-16 ----
__global__ void lif_sum(const float* __restrict__ u, float* __restrict__ hsum) {
    int tid = blockIdx.x * 256 + threadIdx.x;   // 81920
    int b = tid / 2560;
    int cm = tid % 2560;                         // = m*64 + co
    int m = cm >> 6;
    int co = cm & 63;
    const float* up = u + (size_t)b * NT * 2560 + cm;
    float v = 0.f, cnt = 0.f;
    const float TAUc = 10.0f / 7.0f;
    for (int tb = 0; tb < 128; tb += 16) {
        float uu[16];
#pragma unroll
        for (int k = 0; k < 16; k++) uu[k] = up[(size_t)(tb + k) * 2560];
#pragma unroll
        for (int k = 0; k < 16; k++) {
            v = v + (uu[k] - v) / TAUc;
            if (v >= 1.0f) { cnt += 1.0f; v = 0.f; }
        }
    }
    float uu = up[(size_t)128 * 2560];
    v = v + (uu - v) / TAUc;
    if (v >= 1.0f) cnt += 1.0f;
    hsum[b * 2560 + co * NM + m] = cnt;          // feature index = c*40 + m
}

// ---- FC on counts: y[b,k] = bf[k] + (sum_cm cnt*wf[k,cm]) / 129 ----
__global__ void fc_out(const float* __restrict__ hsum, const float* __restrict__ wf,
                       const float* __restrict__ bfv, float* __restrict__ out) {
    int b = blockIdx.x;
    int tid = threadIdx.x;
    float p[12];
#pragma unroll
    for (int k = 0; k < 12; k++) p[k] = 0.0f;
    for (int cm = tid; cm < NC * NM; cm += 256) {
        float h = hsum[b * NC * NM + cm];
#pragma unroll
        for (int k = 0; k < 12; k++) p[k] += h * wf[k * (NC * NM) + cm];
    }
    __shared__ float red[12][4];
    int lane = tid & 63, w = tid >> 6;
#pragma unroll
    for (int k = 0; k < 12; k++) {
        float s = p[k];
#pragma unroll
        for (int off = 32; off > 0; off >>= 1) s += __shfl_down(s, off, 64);
        if (lane == 0) red[k][w] = s;
    }
    __syncthreads();
    if (tid < 12) {
        float s = red[tid][0] + red[tid][1] + red[tid][2] + red[tid][3];
        out[b * 12 + tid] = bfv[tid] + s / 129.0f;
    }
}

extern "C" void kernel_launch(void* const* d_in, const int* in_sizes, int n_in,
                              void* d_out, int out_size, void* d_ws, size_t ws_size,
                              hipStream_t stream) {
    const float* x  = (const float*)d_in[0];
    const float* w1 = (const float*)d_in[1];
    const float* w2 = (const float*)d_in[2];
    const float* w3 = (const float*)d_in[3];
    const float* wf = (const float*)d_in[4];
    const float* bf = (const float*)d_in[5];
    float* out = (float*)d_out;

    char* ws = (char*)d_ws;
    half_t* s1  = (half_t*)ws;                      // 21,135,360 B
    half_t* s2  = (half_t*)(ws + 21135360);         // 21,135,360 B
    float*  u   = (float*)(ws + 42270720);          // 42,270,720 B
    uint4*  wf2 = (uint4*)(ws + 84541440);          // 196,608 B
    uint4*  wf3 = (uint4*)(ws + 84738048);          // 196,608 B
    float* hsum = (float*)(ws + 84934656);          // 327,680 B (end ~85.3 MB)

    constexpr int LDS_CONV = 63552 + 32768;         // 96,320 B (spike+zero+A dbuf)
    static bool attr_set = false;
    if (!attr_set) {
        hipFuncSetAttribute((const void*)&convW<4, 6, 3, 3, 4>,
                            hipFuncAttributeMaxDynamicSharedMemorySize, LDS_CONV);
        hipFuncSetAttribute((const void*)&convW<16, 24, 9, 9, 16>,
                            hipFuncAttributeMaxDynamicSharedMemorySize, LDS_CONV);
        attr_set = true;
    }

    prep_wfrag<<<48, 256, 0, stream>>>(w2, wf2);
    prep_wfrag<<<48, 256, 0, stream>>>(w3, wf3);

    conv1_lif1<<<dim3(10, 32), 256, 0, stream>>>(x, w1, s1);

    convW<4, 6, 3, 3, 4><<<dim3(17, 32), 512, LDS_CONV, stream>>>(s1, wf2, u);
    lif_spikes<<<320, 256, 0, stream>>>(u, s2);

    convW<16, 24, 9, 9, 16><<<dim3(17, 32), 512, LDS_CONV, stream>>>(s2, wf3, u);
    lif_sum<<<320, 256, 0, stream>>>(u, hsum);

    fc_out<<<32, 256, 0, stream>>>(hsum, wf, bf, out);
}

// Round 3
// 243.755 us; speedup vs baseline: 1.1511x; 1.0187x over previous
//
#include <hip/hip_runtime.h>

// SNN forward, round 7.
// Theory: convW was LDS-pipe-throughput bound (160 b128 reads/CU/tap = ~1900cy
// vs 384cy MFMA/SIMD). Fixes: (1) spike tile stored as i8 (spikes are exactly
// 0/1), read b64 + exact VALU expand to f16 (x*0x3C00); (2) A-frags read from
// global/L2 (wfrag stays L2-hot), K-loop is one barrier-free basic block;
// (3) r4 wave shape: 4 waves, acc[3mt][2ct][2hl]=192 regs, 12 MFMA per
// (tap,cq) from 3 B-reads -> LDS/MFMA balanced. LDS 36KB -> 2 blocks/CU via
// __launch_bounds__(256,2). s1/s2 are i8 end-to-end (halves spike HBM traffic).
// u accumulation order identical to r4/r5/r6 -> bit-exact.

typedef __attribute__((ext_vector_type(8))) _Float16 v8h;
typedef __attribute__((ext_vector_type(16))) float v16f;
typedef _Float16 half_t;

#define NB 32
#define NC 64
#define NT 129
#define TIN 128
#define NM 40
#define MS8 80            // i8 LDS slot stride (64B data + 16B pad) -> quad step 5
#define ROWB8 3280        // 41 slots * 80; slot 40 = zero column (OOB m reads)
#define SROWB8 2560       // global spike row bytes = 40*64 (i8)

// ---- weights -> MFMA A-fragments, order [tap12][cq4][ct2][hl2][lane64]x16B ----
// A-frag (32x32x16 f16): lane holds A[co=ct*32+(lane&31)][ci=cq*16+(lane>>5)*8+jj]
__global__ void prep_wfrag(const float* __restrict__ w, uint4* __restrict__ wf) {
    int tid = blockIdx.x * 256 + threadIdx.x;   // 12288
    if (tid >= 12288) return;
    int lane = tid & 63;
    int rest = tid >> 6;
    int hl = rest & 1;
    int ct = (rest >> 1) & 1;
    int cq = (rest >> 2) & 3;
    int tap = rest >> 4;
    int kh = tap / 3, kw = tap % 3;
    int co = ct * 32 + (lane & 31);
    unsigned short o[8];
#pragma unroll
    for (int jj = 0; jj < 8; jj++) {
        int ci = cq * 16 + (lane >> 5) * 8 + jj;
        float wv = w[((co * 64 + ci) * 4 + kh) * 3 + kw];
        _Float16 hi = (_Float16)wv;
        _Float16 val = hl ? (_Float16)((wv - (float)hi) * 2048.0f) : hi;
        unsigned short us;
        __builtin_memcpy(&us, &val, 2);
        o[jj] = us;
    }
    uint4 r;
    __builtin_memcpy(&r, o, 16);
    wf[tid] = r;
}

// ---- conv1 (1->64ch, 4x3, pad(2,1)) + LIF1 -> i8 spikes ----
__global__ void conv1_lif1(const float* __restrict__ x, const float* __restrict__ w1,
                           unsigned char* __restrict__ s1) {
    const int mg = blockIdx.x;        // 0..9
    const int b = blockIdx.y;
    const int c = threadIdx.x & 63;
    const int ml = threadIdx.x >> 6;  // 0..3
    const int m = mg * 4 + ml;
    float w[4][3];
#pragma unroll
    for (int kh = 0; kh < 4; kh++)
#pragma unroll
        for (int kw = 0; kw < 3; kw++) w[kh][kw] = w1[(c * 4 + kh) * 3 + kw];
    const float* xb = x + (size_t)b * TIN * NM;

    float xw[12][3];                  // rows tb-2 .. tb+9
#pragma unroll
    for (int rr = 0; rr < 12; rr++)
#pragma unroll
        for (int kw = 0; kw < 3; kw++) xw[rr][kw] = 0.f;
#pragma unroll
    for (int rr = 2; rr < 4; rr++)
#pragma unroll
        for (int kw = 0; kw < 3; kw++) {
            int mc = m - 1 + kw;
            xw[rr][kw] = ((unsigned)mc < (unsigned)NM) ? xb[(rr - 2) * NM + mc] : 0.f;
        }

    unsigned char* orow = s1 + ((size_t)b * NT * NM + m) * 64 + c;
    float v = 0.f;
    const float TAUc = 10.0f / 7.0f;

    for (int tb = 0; tb < NT; tb += 8) {
#pragma unroll
        for (int q = 0; q < 8; q++) {
            int row = tb + 2 + q;
#pragma unroll
            for (int kw = 0; kw < 3; kw++) {
                int mc = m - 1 + kw;
                xw[4 + q][kw] = (row < TIN && (unsigned)mc < (unsigned)NM)
                                    ? xb[row * NM + mc] : 0.f;
            }
        }
        int kmax = (NT - tb) < 8 ? (NT - tb) : 8;
#pragma unroll
        for (int k = 0; k < 8; k++) {
            if (k < kmax) {
                float uacc = 0.f;
#pragma unroll
                for (int kh = 0; kh < 4; kh++)
#pragma unroll
                    for (int kw = 0; kw < 3; kw++) uacc += xw[k + kh][kw] * w[kh][kw];
                v = v + (uacc - v) / TAUc;
                orow[(size_t)(tb + k) * NM * 64] = (v >= 1.0f) ? 1 : 0;
                if (v >= 1.0f) v = 0.0f;
            }
        }
#pragma unroll
        for (int rr = 0; rr < 4; rr++)
#pragma unroll
            for (int kw = 0; kw < 3; kw++) xw[rr][kw] = xw[8 + rr][kw];
    }
}

// ---- exact i8{0,1} -> f16{0,1.0} expansion: (b0 | b1<<16) * 0x3C00 ----
__device__ inline v8h expand01(uint2 raw) {
    unsigned x0 = raw.x, x1 = raw.y;
    unsigned o0 = ((x0 & 0xFFu) | (((x0 >> 8) & 0xFFu) << 16)) * 0x3C00u;
    unsigned o1 = (((x0 >> 16) & 0xFFu) | ((x0 >> 24) << 16)) * 0x3C00u;
    unsigned o2 = ((x1 & 0xFFu) | (((x1 >> 8) & 0xFFu) << 16)) * 0x3C00u;
    unsigned o3 = (((x1 >> 16) & 0xFFu) | ((x1 >> 24) << 16)) * 0x3C00u;
    uint4 o = make_uint4(o0, o1, o2, o3);
    return __builtin_bit_cast(v8h, o);
}

// ---- MFMA conv 64->64, 4x3 dilated. i8 spike tile in LDS, A from global/L2.
// grid (17, B) x 256 thr = 4 waves; wave wp owns jj-pair (jj0+2wp, jj0+2wp+1)
// x 3 m-tiles {0,16,24} x 2ct x 2hl = 12 accs (192 VGPRs). Barrier-free K-loop.
template <int DH, int PH, int DW, int PW, int RMOD>
__global__ __launch_bounds__(256, 2) void convW(const unsigned char* __restrict__ spk,
                                                const uint4* __restrict__ wfrag,
                                                float* __restrict__ u) {
    __shared__ uint4 ldsq[11 * ROWB8 / 16];     // 36,080 B
    char* lds = (char*)ldsq;
    const int tid = threadIdx.x;
    const int lane = tid & 63;
    const int wp = tid >> 6;                    // 0..3
    const int bx = blockIdx.x;
    const int b = blockIdx.y;
    int r, jj0;
    if (bx < 16) { r = bx % RMOD; jj0 = (bx / RMOD) * 8; }
    else         { r = 0;         jj0 = (16 / RMOD) * 8; }

    // ---- stage 11 lattice rows x 41 slots (slot 40 = zeros) x 4 chunks ----
    const char* spb = (const char*)spk + (size_t)b * NT * SROWB8;
#pragma unroll
    for (int k = 0; k < 8; k++) {
        int c = tid + k * 256;
        if (c < 1804) {
            int i = c / 164;
            int rem = c - i * 164;
            int s = rem >> 2;                   // m-slot 0..40
            int q = rem & 3;
            int tg = r - PH + DH * (jj0 + i);
            uint4 val = make_uint4(0u, 0u, 0u, 0u);
            if ((unsigned)tg < (unsigned)NT && s < 40)
                val = *(const uint4*)(spb + ((size_t)tg * NM + s) * 64 + q * 16);
            *(uint4*)(lds + i * ROWB8 + s * MS8 + q * 16) = val;
        }
    }
    __syncthreads();

    // ---- lane decode: pos-tile = 2jj x 16m ----
    const int pos = lane & 31;
    const int jl = pos >> 4;
    const int ml = pos & 15;
    const int hseg = lane >> 5;
    const int jj = jj0 + 2 * wp + jl;
    const int ldsrow = 2 * wp + jl;             // 0..7
    const int t = r + DH * jj;
    const int mtb[3] = {0, 16, 24};

    // B-read bases: OOB m -> zero column (slot 40), row step uniform ROWB8
    int P[3][3];
#pragma unroll
    for (int mt = 0; mt < 3; mt++)
#pragma unroll
        for (int kw = 0; kw < 3; kw++) {
            int md = mtb[mt] + ml + kw * DW - PW;
            int sel = ((unsigned)md < 40u) ? md : 40;
            P[mt][kw] = ldsrow * ROWB8 + sel * MS8 + hseg * 8;
        }

    v16f acc[3][2][2];                          // [m-tile][co-tile][hi/lo]
#pragma unroll
    for (int a = 0; a < 3; a++)
#pragma unroll
        for (int c2 = 0; c2 < 2; c2++)
#pragma unroll
            for (int h = 0; h < 2; h++) acc[a][c2][h] = (v16f)(0.0f);

    // ---- barrier-free K-loop: 48 steps, one basic block ----
#pragma unroll
    for (int tap = 0; tap < 12; tap++) {
        const int kh = tap / 3, kw = tap % 3;
#pragma unroll
        for (int cq = 0; cq < 4; cq++) {
            const uint4* wq = wfrag + (tap * 4 + cq) * 256 + lane;
            uint4 a00 = wq[0];                  // ct0 hi
            uint4 a01 = wq[64];                 // ct0 lo
            uint4 a10 = wq[128];                // ct1 hi
            uint4 a11 = wq[192];                // ct1 lo
            uint2 r0 = *(const uint2*)(lds + P[0][kw] + kh * ROWB8 + cq * 16);
            uint2 r1 = *(const uint2*)(lds + P[1][kw] + kh * ROWB8 + cq * 16);
            uint2 r2 = *(const uint2*)(lds + P[2][kw] + kh * ROWB8 + cq * 16);
            v8h B0 = expand01(r0);
            v8h B1 = expand01(r1);
            v8h B2 = expand01(r2);
            v8h A00 = __builtin_bit_cast(v8h, a00);
            v8h A01 = __builtin_bit_cast(v8h, a01);
            v8h A10 = __builtin_bit_cast(v8h, a10);
            v8h A11 = __builtin_bit_cast(v8h, a11);
            acc[0][0][0] = __builtin_amdgcn_mfma_f32_32x32x16_f16(A00, B0, acc[0][0][0], 0, 0, 0);
            acc[0][0][1] = __builtin_amdgcn_mfma_f32_32x32x16_f16(A01, B0, acc[0][0][1], 0, 0, 0);
            acc[0][1][0] = __builtin_amdgcn_mfma_f32_32x32x16_f16(A10, B0, acc[0][1][0], 0, 0, 0);
            acc[0][1][1] = __builtin_amdgcn_mfma_f32_32x32x16_f16(A11, B0, acc[0][1][1], 0, 0, 0);
            acc[1][0][0] = __builtin_amdgcn_mfma_f32_32x32x16_f16(A00, B1, acc[1][0][0], 0, 0, 0);
            acc[1][0][1] = __builtin_amdgcn_mfma_f32_32x32x16_f16(A01, B1, acc[1][0][1], 0, 0, 0);
            acc[1][1][0] = __builtin_amdgcn_mfma_f32_32x32x16_f16(A10, B1, acc[1][1][0], 0, 0, 0);
            acc[1][1][1] = __builtin_amdgcn_mfma_f32_32x32x16_f16(A11, B1, acc[1][1][1], 0, 0, 0);
            acc[2][0][0] = __builtin_amdgcn_mfma_f32_32x32x16_f16(A00, B2, acc[2][0][0], 0, 0, 0);
            acc[2][0][1] = __builtin_amdgcn_mfma_f32_32x32x16_f16(A01, B2, acc[2][0][1], 0, 0, 0);
            acc[2][1][0] = __builtin_amdgcn_mfma_f32_32x32x16_f16(A10, B2, acc[2][1][0], 0, 0, 0);
            acc[2][1][1] = __builtin_amdgcn_mfma_f32_32x32x16_f16(A11, B2, acc[2][1][1], 0, 0, 0);
        }
    }

    // ---- epilogue: u = hi + lo/2048 (m24..31 double-written, identical) ----
    const float invs = 1.0f / 2048.0f;
    if (t < NT) {
#pragma unroll
        for (int mt = 0; mt < 3; mt++) {
            int m = mtb[mt] + ml;
            float* base = u + ((size_t)(b * NT + t) * NM + m) * 64;
#pragma unroll
            for (int ct = 0; ct < 2; ct++) {
#pragma unroll
                for (int g = 0; g < 4; g++) {
                    int co = ct * 32 + 8 * g + 4 * hseg;
                    float4 val;
                    val.x = acc[mt][ct][0][4 * g + 0] + acc[mt][ct][1][4 * g + 0] * invs;
                    val.y = acc[mt][ct][0][4 * g + 1] + acc[mt][ct][1][4 * g + 1] * invs;
                    val.z = acc[mt][ct][0][4 * g + 2] + acc[mt][ct][1][4 * g + 2] * invs;
                    val.w = acc[mt][ct][0][4 * g + 3] + acc[mt][ct][1][4 * g + 3] * invs;
                    *(float4*)(base + co) = val;
                }
            }
        }
    }
}

// ---- LIF over T: u fp32 -> i8 spikes, unroll-16 ----
__global__ void lif_spikes(const float* __restrict__ u, unsigned char* __restrict__ s2) {
    int tid = blockIdx.x * 256 + threadIdx.x;   // 81920
    int b = tid / 2560;
    int cm = tid % 2560;
    const float* up = u + (size_t)b * NT * 2560 + cm;
    unsigned char* sp = s2 + (size_t)b * NT * 2560 + cm;
    float v = 0.f;
    const float TAUc = 10.0f / 7.0f;
    for (int tb = 0; tb < 128; tb += 16) {
        float uu[16];
#pragma unroll
        for (int k = 0; k < 16; k++) uu[k] = up[(size_t)(tb + k) * 2560];
#pragma unroll
        for (int k = 0; k < 16; k++) {
            v = v + (uu[k] - v) / TAUc;
            sp[(size_t)(tb + k) * 2560] = (v >= 1.0f) ? 1 : 0;
            if (v >= 1.0f) v = 0.f;
        }
    }
    float uu = up[(size_t)128 * 2560];
    v = v + (uu - v) / TAUc;
    sp[(size_t)128 * 2560] = (v >= 1.0f) ? 1 : 0;
}

// ---- LIF3: spike counts only (mean commutes with FC), unroll-16 ----
__global__ void lif_sum(const float* __restrict__ u, float* __restrict__ hsum) {
    int tid = blockIdx.x * 256 + threadIdx.x;   // 81920
    int b = tid / 2560;
    int cm = tid % 2560;                         // = m*64 + co
    int m = cm >> 6;
    int co = cm & 63;
    const float* up = u + (size_t)b * NT * 2560 + cm;
    float v = 0.f, cnt = 0.f;
    const float TAUc = 10.0f / 7.0f;
    for (int tb = 0; tb < 128; tb += 16) {
        float uu[16];
#pragma unroll
        for (int k = 0; k < 16; k++) uu[k] = up[(size_t)(tb + k) * 2560];
#pragma unroll
        for (int k = 0; k < 16; k++) {
            v = v + (uu[k] - v) / TAUc;
            if (v >= 1.0f) { cnt += 1.0f; v = 0.f; }
        }
    }
    float uu = up[(size_t)128 * 2560];
    v = v + (uu - v) / TAUc;
    if (v >= 1.0f) cnt += 1.0f;
    hsum[b * 2560 + co * NM + m] = cnt;          // feature index = c*40 + m
}

// ---- FC on counts: y[b,k] = bf[k] + (sum_cm cnt*wf[k,cm]) / 129 ----
__global__ void fc_out(const float* __restrict__ hsum, const float* __restrict__ wf,
                       const float* __restrict__ bfv, float* __restrict__ out) {
    int b = blockIdx.x;
    int tid = threadIdx.x;
    float p[12];
#pragma unroll
    for (int k = 0; k < 12; k++) p[k] = 0.0f;
    for (int cm = tid; cm < NC * NM; cm += 256) {
        float h = hsum[b * NC * NM + cm];
#pragma unroll
        for (int k = 0; k < 12; k++) p[k] += h * wf[k * (NC * NM) + cm];
    }
    __shared__ float red[12][4];
    int lane = tid & 63, w = tid >> 6;
#pragma unroll
    for (int k = 0; k < 12; k++) {
        float s = p[k];
#pragma unroll
        for (int off = 32; off > 0; off >>= 1) s += __shfl_down(s, off, 64);
        if (lane == 0) red[k][w] = s;
    }
    __syncthreads();
    if (tid < 12) {
        float s = red[tid][0] + red[tid][1] + red[tid][2] + red[tid][3];
        out[b * 12 + tid] = bfv[tid] + s / 129.0f;
    }
}

extern "C" void kernel_launch(void* const* d_in, const int* in_sizes, int n_in,
                              void* d_out, int out_size, void* d_ws, size_t ws_size,
                              hipStream_t stream) {
    const float* x  = (const float*)d_in[0];
    const float* w1 = (const float*)d_in[1];
    const float* w2 = (const float*)d_in[2];
    const float* w3 = (const float*)d_in[3];
    const float* wf = (const float*)d_in[4];
    const float* bf = (const float*)d_in[5];
    float* out = (float*)d_out;

    char* ws = (char*)d_ws;
    unsigned char* s1 = (unsigned char*)ws;          // 10,567,680 B (i8 spikes)
    unsigned char* s2 = (unsigned char*)(ws + 10567680); // 10,567,680 B
    float*  u   = (float*)(ws + 21135360);           // 42,270,720 B
    uint4*  wf2 = (uint4*)(ws + 63406080);           // 196,608 B
    uint4*  wf3 = (uint4*)(ws + 63602688);           // 196,608 B
    float* hsum = (float*)(ws + 63799296);           // 327,680 B (end ~64.1 MB)

    prep_wfrag<<<48, 256, 0, stream>>>(w2, wf2);
    prep_wfrag<<<48, 256, 0, stream>>>(w3, wf3);

    conv1_lif1<<<dim3(10, 32), 256, 0, stream>>>(x, w1, s1);

    convW<4, 6, 3, 3, 4><<<dim3(17, 32), 256, 0, stream>>>(s1, wf2, u);
    lif_spikes<<<320, 256, 0, stream>>>(u, s2);

    convW<16, 24, 9, 9, 16><<<dim3(17, 32), 256, 0, stream>>>(s2, wf3, u);
    lif_sum<<<320, 256, 0, stream>>>(u, hsum);

    fc_out<<<32, 256, 0, stream>>>(hsum, wf, bf, out);
}

// Round 4
// 218.899 us; speedup vs baseline: 1.2818x; 1.1136x over previous
//
#include <hip/hip_runtime.h>

// SNN forward, round 8.
// convW: barrier-free K-loop (r7) x multi-wave-per-SIMD (r5) — the untested
// combination. 4-wave blocks: 2 jj-pairs x 2 hl; 96 acc regs/wave; 7 lattice
// rows in 22.9KB LDS; grid (33,B). __launch_bounds__(256,3) -> 3 blocks/CU =
// 3 independent (non-barrier-coupled) waves/SIMD to fill the ~60% per-wave
// stall. i8 spike expand via v_perm_b32 + mul (8 VALU / B-frag). hi+lo
// recombined through LDS with identical expression/order -> bit-exact.

typedef __attribute__((ext_vector_type(8))) _Float16 v8h;
typedef __attribute__((ext_vector_type(16))) float v16f;
typedef _Float16 half_t;

#define NB 32
#define NC 64
#define NT 129
#define TIN 128
#define NM 40
#define MS8 80            // i8 LDS slot stride
#define ROWB8 3280        // 41 slots * 80; slot 40 = zero column
#define SROWB8 2560       // global spike row bytes = 40*64 (i8)

// ---- weights -> MFMA A-fragments, order [tap12][cq4][ct2][hl2][lane64]x16B ----
__global__ void prep_wfrag(const float* __restrict__ w, uint4* __restrict__ wf) {
    int tid = blockIdx.x * 256 + threadIdx.x;   // 12288
    if (tid >= 12288) return;
    int lane = tid & 63;
    int rest = tid >> 6;
    int hl = rest & 1;
    int ct = (rest >> 1) & 1;
    int cq = (rest >> 2) & 3;
    int tap = rest >> 4;
    int kh = tap / 3, kw = tap % 3;
    int co = ct * 32 + (lane & 31);
    unsigned short o[8];
#pragma unroll
    for (int jj = 0; jj < 8; jj++) {
        int ci = cq * 16 + (lane >> 5) * 8 + jj;
        float wv = w[((co * 64 + ci) * 4 + kh) * 3 + kw];
        _Float16 hi = (_Float16)wv;
        _Float16 val = hl ? (_Float16)((wv - (float)hi) * 2048.0f) : hi;
        unsigned short us;
        __builtin_memcpy(&us, &val, 2);
        o[jj] = us;
    }
    uint4 r;
    __builtin_memcpy(&r, o, 16);
    wf[tid] = r;
}

// ---- conv1 (1->64ch, 4x3, pad(2,1)) + LIF1 -> i8 spikes ----
__global__ void conv1_lif1(const float* __restrict__ x, const float* __restrict__ w1,
                           unsigned char* __restrict__ s1) {
    const int mg = blockIdx.x;        // 0..9
    const int b = blockIdx.y;
    const int c = threadIdx.x & 63;
    const int ml = threadIdx.x >> 6;  // 0..3
    const int m = mg * 4 + ml;
    float w[4][3];
#pragma unroll
    for (int kh = 0; kh < 4; kh++)
#pragma unroll
        for (int kw = 0; kw < 3; kw++) w[kh][kw] = w1[(c * 4 + kh) * 3 + kw];
    const float* xb = x + (size_t)b * TIN * NM;

    float xw[12][3];                  // rows tb-2 .. tb+9
#pragma unroll
    for (int rr = 0; rr < 12; rr++)
#pragma unroll
        for (int kw = 0; kw < 3; kw++) xw[rr][kw] = 0.f;
#pragma unroll
    for (int rr = 2; rr < 4; rr++)
#pragma unroll
        for (int kw = 0; kw < 3; kw++) {
            int mc = m - 1 + kw;
            xw[rr][kw] = ((unsigned)mc < (unsigned)NM) ? xb[(rr - 2) * NM + mc] : 0.f;
        }

    unsigned char* orow = s1 + ((size_t)b * NT * NM + m) * 64 + c;
    float v = 0.f;
    const float TAUc = 10.0f / 7.0f;

    for (int tb = 0; tb < NT; tb += 8) {
#pragma unroll
        for (int q = 0; q < 8; q++) {
            int row = tb + 2 + q;
#pragma unroll
            for (int kw = 0; kw < 3; kw++) {
                int mc = m - 1 + kw;
                xw[4 + q][kw] = (row < TIN && (unsigned)mc < (unsigned)NM)
                                    ? xb[row * NM + mc] : 0.f;
            }
        }
        int kmax = (NT - tb) < 8 ? (NT - tb) : 8;
#pragma unroll
        for (int k = 0; k < 8; k++) {
            if (k < kmax) {
                float uacc = 0.f;
#pragma unroll
                for (int kh = 0; kh < 4; kh++)
#pragma unroll
                    for (int kw = 0; kw < 3; kw++) uacc += xw[k + kh][kw] * w[kh][kw];
                v = v + (uacc - v) / TAUc;
                orow[(size_t)(tb + k) * NM * 64] = (v >= 1.0f) ? 1 : 0;
                if (v >= 1.0f) v = 0.0f;
            }
        }
#pragma unroll
        for (int rr = 0; rr < 4; rr++)
#pragma unroll
            for (int kw = 0; kw < 3; kw++) xw[rr][kw] = xw[8 + rr][kw];
    }
}

// ---- exact i8{0,1} -> f16{0,1.0}: v_perm byte spread + *0x3C00 ----
__device__ inline v8h expand01(uint2 raw) {
    unsigned o0 = __builtin_amdgcn_perm(0u, raw.x, 0x04010400u) * 0x3C00u;
    unsigned o1 = __builtin_amdgcn_perm(0u, raw.x, 0x04030402u) * 0x3C00u;
    unsigned o2 = __builtin_amdgcn_perm(0u, raw.y, 0x04010400u) * 0x3C00u;
    unsigned o3 = __builtin_amdgcn_perm(0u, raw.y, 0x04030402u) * 0x3C00u;
    uint4 o = make_uint4(o0, o1, o2, o3);
    return __builtin_bit_cast(v8h, o);
}

// ---- MFMA conv 64->64, 4x3 dilated. 4 waves = 2 jj-pairs x 2 hl.
// grid (33, B) x 256 thr. bx<32: r = bx%RMOD, jj0 = (bx/RMOD)*4; bx==32: r=0,
// jj0=(32/RMOD)*4. Wave wv: wp=wv>>1 owns jj-pair (jj0+2wp, jj0+2wp+1) x 3
// m-tiles {0,16,24}; hl=wv&1 -> 6 accs (96 regs). Barrier-free K-loop;
// 3 blocks/CU give 3 independent waves/SIMD.
template <int DH, int PH, int DW, int PW, int RMOD>
__global__ __launch_bounds__(256, 3) void convW(const unsigned char* __restrict__ spk,
                                                const uint4* __restrict__ wfrag,
                                                float* __restrict__ u) {
    __shared__ uint4 ldsq[7 * ROWB8 / 16];      // 22,960 B
    char* lds = (char*)ldsq;
    const int tid = threadIdx.x;
    const int lane = tid & 63;
    const int wv = tid >> 6;                    // 0..3
    const int wp = wv >> 1;                     // 0..1 jj-pair
    const int hl = wv & 1;                      // 0=hi, 1=lo
    const int bx = blockIdx.x;
    const int b = blockIdx.y;
    int r, jj0;
    if (bx < 32) { r = bx % RMOD; jj0 = (bx / RMOD) * 4; }
    else         { r = 0;         jj0 = (32 / RMOD) * 4; }

    // ---- stage 7 lattice rows x 41 slots (slot 40 = zeros) x 4 chunks ----
    const char* spb = (const char*)spk + (size_t)b * NT * SROWB8;
#pragma unroll
    for (int k = 0; k < 5; k++) {
        int c = tid + k * 256;
        if (c < 1148) {
            int i = c / 164;
            int rem = c - i * 164;
            int s = rem >> 2;                   // m-slot 0..40
            int q = rem & 3;
            int tg = r - PH + DH * (jj0 + i);
            uint4 val = make_uint4(0u, 0u, 0u, 0u);
            if ((unsigned)tg < (unsigned)NT && s < 40)
                val = *(const uint4*)(spb + ((size_t)tg * NM + s) * 64 + q * 16);
            *(uint4*)(lds + i * ROWB8 + s * MS8 + q * 16) = val;
        }
    }
    __syncthreads();

    // ---- lane decode: pos-tile = 2jj x 16m ----
    const int pos = lane & 31;
    const int jl = pos >> 4;
    const int ml = pos & 15;
    const int hseg = lane >> 5;
    const int jj = jj0 + 2 * wp + jl;
    const int ldsrow = 2 * wp + jl;             // 0..3
    const int t = r + DH * jj;
    const int mtb[3] = {0, 16, 24};

    // B-read bases: OOB m -> zero column (slot 40); row step uniform ROWB8
    int P[3][3];
#pragma unroll
    for (int mt = 0; mt < 3; mt++)
#pragma unroll
        for (int kw = 0; kw < 3; kw++) {
            int md = mtb[mt] + ml + kw * DW - PW;
            int sel = ((unsigned)md < 40u) ? md : 40;
            P[mt][kw] = ldsrow * ROWB8 + sel * MS8 + hseg * 8;
        }

    v16f acc[3][2];                             // [m-tile][co-tile], one hl stream
#pragma unroll
    for (int a = 0; a < 3; a++)
#pragma unroll
        for (int c2 = 0; c2 < 2; c2++) acc[a][c2] = (v16f)(0.0f);

    const int hl64 = hl * 64;
    // ---- barrier-free K-loop: 48 steps, one basic block ----
#pragma unroll
    for (int tap = 0; tap < 12; tap++) {
        const int kh = tap / 3, kw = tap % 3;
#pragma unroll
        for (int cq = 0; cq < 4; cq++) {
            const uint4* wq = wfrag + (tap * 4 + cq) * 256 + hl64 + lane;
            uint4 a0 = wq[0];                   // ct0, this hl
            uint4 a1 = wq[128];                 // ct1, this hl
            uint2 r0 = *(const uint2*)(lds + P[0][kw] + kh * ROWB8 + cq * 16);
            uint2 r1 = *(const uint2*)(lds + P[1][kw] + kh * ROWB8 + cq * 16);
            uint2 r2 = *(const uint2*)(lds + P[2][kw] + kh * ROWB8 + cq * 16);
            v8h B0 = expand01(r0);
            v8h B1 = expand01(r1);
            v8h B2 = expand01(r2);
            v8h A0 = __builtin_bit_cast(v8h, a0);
            v8h A1 = __builtin_bit_cast(v8h, a1);
            acc[0][0] = __builtin_amdgcn_mfma_f32_32x32x16_f16(A0, B0, acc[0][0], 0, 0, 0);
            acc[0][1] = __builtin_amdgcn_mfma_f32_32x32x16_f16(A1, B0, acc[0][1], 0, 0, 0);
            acc[1][0] = __builtin_amdgcn_mfma_f32_32x32x16_f16(A0, B1, acc[1][0], 0, 0, 0);
            acc[1][1] = __builtin_amdgcn_mfma_f32_32x32x16_f16(A1, B1, acc[1][1], 0, 0, 0);
            acc[2][0] = __builtin_amdgcn_mfma_f32_32x32x16_f16(A0, B2, acc[2][0], 0, 0, 0);
            acc[2][1] = __builtin_amdgcn_mfma_f32_32x32x16_f16(A1, B2, acc[2][1], 0, 0, 0);
        }
    }

    // ---- combine: lo wave -> LDS (reuse tile), hi wave adds+writes.
    // u = hi + lo/2048, identical arithmetic/order (bit-exact).
    const float invs = 1.0f / 2048.0f;
    float4* lred = (float4*)lds;                // 2 wp x 8 chunks x 64 lanes x 16B = 16KB
    __syncthreads();                            // all K-loop LDS reads done
#pragma unroll
    for (int mt = 0; mt < 3; mt++) {
        if (hl) {
#pragma unroll
            for (int ct = 0; ct < 2; ct++)
#pragma unroll
                for (int g = 0; g < 4; g++) {
                    float4 vv;
                    vv.x = acc[mt][ct][4 * g + 0];
                    vv.y = acc[mt][ct][4 * g + 1];
                    vv.z = acc[mt][ct][4 * g + 2];
                    vv.w = acc[mt][ct][4 * g + 3];
                    lred[(wp * 8 + ct * 4 + g) * 64 + lane] = vv;
                }
        }
        __syncthreads();
        if (!hl && t < NT) {
            int m = mtb[mt] + ml;
            float* base = u + ((size_t)(b * NT + t) * NM + m) * 64;
#pragma unroll
            for (int ct = 0; ct < 2; ct++)
#pragma unroll
                for (int g = 0; g < 4; g++) {
                    float4 lo = lred[(wp * 8 + ct * 4 + g) * 64 + lane];
                    int co = ct * 32 + 8 * g + 4 * hseg;
                    float4 val;
                    val.x = acc[mt][ct][4 * g + 0] + lo.x * invs;
                    val.y = acc[mt][ct][4 * g + 1] + lo.y * invs;
                    val.z = acc[mt][ct][4 * g + 2] + lo.z * invs;
                    val.w = acc[mt][ct][4 * g + 3] + lo.w * invs;
                    *(float4*)(base + co) = val;
                }
        }
        __syncthreads();
    }
}

// ---- LIF over T: u fp32 -> i8 spikes, unroll-16 ----
__global__ void lif_spikes(const float* __restrict__ u, unsigned char* __restrict__ s2) {
    int tid = blockIdx.x * 256 + threadIdx.x;   // 81920
    int b = tid / 2560;
    int cm = tid % 2560;
    const float* up = u + (size_t)b * NT * 2560 + cm;
    unsigned char* sp = s2 + (size_t)b * NT * 2560 + cm;
    float v = 0.f;
    const float TAUc = 10.0f / 7.0f;
    for (int tb = 0; tb < 128; tb += 16) {
        float uu[16];
#pragma unroll
        for (int k = 0; k < 16; k++) uu[k] = up[(size_t)(tb + k) * 2560];
#pragma unroll
        for (int k = 0; k < 16; k++) {
            v = v + (uu[k] - v) / TAUc;
            sp[(size_t)(tb + k) * 2560] = (v >= 1.0f) ? 1 : 0;
            if (v >= 1.0f) v = 0.f;
        }
    }
    float uu = up[(size_t)128 * 2560];
    v = v + (uu - v) / TAUc;
    sp[(size_t)128 * 2560] = (v >= 1.0f) ? 1 : 0;
}

// ---- LIF3: spike counts only (mean commutes with FC), unroll-16 ----
__global__ void lif_sum(const float* __restrict__ u, float* __restrict__ hsum) {
    int tid = blockIdx.x * 256 + threadIdx.x;   // 81920
    int b = tid / 2560;
    int cm = tid % 2560;                         // = m*64 + co
    int m = cm >> 6;
    int co = cm & 63;
    const float* up = u + (size_t)b * NT * 2560 + cm;
    float v = 0.f, cnt = 0.f;
    const float TAUc = 10.0f / 7.0f;
    for (int tb = 0; tb < 128; tb += 16) {
        float uu[16];
#pragma unroll
        for (int k = 0; k < 16; k++) uu[k] = up[(size_t)(tb + k) * 2560];
#pragma unroll
        for (int k = 0; k < 16; k++) {
            v = v + (uu[k] - v) / TAUc;
            if (v >= 1.0f) { cnt += 1.0f; v = 0.f; }
        }
    }
    float uu = up[(size_t)128 * 2560];
    v = v + (uu - v) / TAUc;
    if (v >= 1.0f) cnt += 1.0f;
    hsum[b * 2560 + co * NM + m] = cnt;          // feature index = c*40 + m
}

// ---- FC on counts: y[b,k] = bf[k] + (sum_cm cnt*wf[k,cm]) / 129 ----
__global__ void fc_out(const float* __restrict__ hsum, const float* __restrict__ wf,
                       const float* __restrict__ bfv, float* __restrict__ out) {
    int b = blockIdx.x;
    int tid = threadIdx.x;
    float p[12];
#pragma unroll
    for (int k = 0; k < 12; k++) p[k] = 0.0f;
    for (int cm = tid; cm < NC * NM; cm += 256) {
        float h = hsum[b * NC * NM + cm];
#pragma unroll
        for (int k = 0; k < 12; k++) p[k] += h * wf[k * (NC * NM) + cm];
    }
    __shared__ float red[12][4];
    int lane = tid & 63, w = tid >> 6;
#pragma unroll
    for (int k = 0; k < 12; k++) {
        float s = p[k];
#pragma unroll
        for (int off = 32; off > 0; off >>= 1) s += __shfl_down(s, off, 64);
        if (lane == 0) red[k][w] = s;
    }
    __syncthreads();
    if (tid < 12) {
        float s = red[tid][0] + red[tid][1] + red[tid][2] + red[tid][3];
        out[b * 12 + tid] = bfv[tid] + s / 129.0f;
    }
}

extern "C" void kernel_launch(void* const* d_in, const int* in_sizes, int n_in,
                              void* d_out, int out_size, void* d_ws, size_t ws_size,
                              hipStream_t stream) {
    const float* x  = (const float*)d_in[0];
    const float* w1 = (const float*)d_in[1];
    const float* w2 = (const float*)d_in[2];
    const float* w3 = (const float*)d_in[3];
    const float* wf = (const float*)d_in[4];
    const float* bf = (const float*)d_in[5];
    float* out = (float*)d_out;

    char* ws = (char*)d_ws;
    unsigned char* s1 = (unsigned char*)ws;          // 10,567,680 B (i8 spikes)
    unsigned char* s2 = (unsigned char*)(ws + 10567680); // 10,567,680 B
    float*  u   = (float*)(ws + 21135360);           // 42,270,720 B
    uint4*  wf2 = (uint4*)(ws + 63406080);           // 196,608 B
    uint4*  wf3 = (uint4*)(ws + 63602688);           // 196,608 B
    float* hsum = (float*)(ws + 63799296);           // 327,680 B (end ~64.1 MB)

    prep_wfrag<<<48, 256, 0, stream>>>(w2, wf2);
    prep_wfrag<<<48, 256, 0, stream>>>(w3, wf3);

    conv1_lif1<<<dim3(10, 32), 256, 0, stream>>>(x, w1, s1);

    convW<4, 6, 3, 3, 4><<<dim3(33, 32), 256, 0, stream>>>(s1, wf2, u);
    lif_spikes<<<320, 256, 0, stream>>>(u, s2);

    convW<16, 24, 9, 9, 16><<<dim3(33, 32), 256, 0, stream>>>(s2, wf3, u);
    lif_sum<<<320, 256, 0, stream>>>(u, hsum);

    fc_out<<<32, 256, 0, stream>>>(hsum, wf, bf, out);
}